// Round 12
// baseline (45.115 us; speedup 1.0000x reference)
//
#include <hip/hip_runtime.h>
#include <stdint.h>

#define INPUT_SCALE 0.0078125f   // 2^-7

__device__ __forceinline__ uint32_t sadu8(uint32_t a, uint32_t b, uint32_t c) {
#if __has_builtin(__builtin_amdgcn_sad_u8)
    return __builtin_amdgcn_sad_u8(a, b, c);
#else
    uint32_t d;
    asm("v_sad_u8 %0, %1, %2, %3" : "=v"(d) : "v"(a), "v"(b), "v"(c));
    return d;
#endif
}

__device__ __forceinline__ uint32_t qbyte(float x) {
    // round(clip(x*128, -127, 127)) + 128  (rintf = round-half-even, matches jnp.round)
    float v = fminf(fmaxf(x * 128.0f, -127.0f), 127.0f);
    return (uint32_t)((int)rintf(v) + 128);
}

// Padded packed-x geometry: per image 130x130 px, 32 B/px (32 channels, bias +128)
#define PIMG 16900          // 130*130 px per image
#define PROW 130            // px per padded row

// ---------------- Kernel A: weight scale+pack (block 0) + border fill (blocks 1+) ----
// qwp tap-major: u = (t*32 + f)*8 + cg, t = kh*3+kw. One tap = 1 KB contiguous.
__global__ __launch_bounds__(1024) void quant_weight_border(const float* __restrict__ w,
                                                            uint32_t* __restrict__ qwp,
                                                            uint32_t* __restrict__ qxp) {
    int tid = threadIdx.x;
    if (blockIdx.x != 0) {
        // border fill: 16 images x 516 border px, 8 u32 each, value 0x80 (quantized 0)
        int idx = (blockIdx.x - 1) * 1024 + tid;      // 9 blocks x 1024 = 9216 >= 8256
        if (idx < 16 * 516) {
            int n = idx / 516, i = idx - n * 516;
            int r, c;
            if (i < 130)      { r = 0;   c = i; }
            else if (i < 260) { r = 129; c = i - 130; }
            else if (i < 388) { r = 1 + (i - 260); c = 0; }
            else              { r = 1 + (i - 388); c = 129; }
            uint4* p = (uint4*)(qxp + ((size_t)n * PIMG + r * PROW + c) * 8);
            uint4 v = make_uint4(0x80808080u, 0x80808080u, 0x80808080u, 0x80808080u);
            p[0] = v; p[1] = v;
        }
        return;
    }
    __shared__ float red[1024];
    __shared__ float s_inv;
    float m = 0.0f;
    for (int i = tid; i < 9216; i += 1024) m = fmaxf(m, fabsf(w[i]));
    red[tid] = m;
    __syncthreads();
    for (int s = 512; s > 0; s >>= 1) {
        if (tid < s) red[tid] = fmaxf(red[tid], red[tid + s]);
        __syncthreads();
    }
    if (tid == 0) {
        float s = fmaxf(red[0] / 127.0f, 1e-8f);
        int e; float fr = frexpf(s, &e);            // s = fr * 2^e, fr in [0.5,1)
        int k = (fr >= 0.70710678118654752f) ? e : e - 1;  // round(log2(s))
        s_inv = exp2f((float)(-k));                 // 1/s_w, exact power of 2
    }
    __syncthreads();
    float inv = s_inv;
    for (int u = tid; u < 2304; u += 1024) {
        int t = u >> 8;            // tap 0..8
        int rem = u & 255;
        int f = rem >> 3, cg = rem & 7;
        int kh = t / 3, kw = t - kh * 3;
        uint32_t pk = 0;
        #pragma unroll
        for (int b = 0; b < 4; ++b) {
            int c = cg * 4 + b;
            float v = w[((f * 32 + c) * 3 + kh) * 3 + kw] * inv;
            v = fminf(fmaxf(v, -127.0f), 127.0f);
            pk |= ((uint32_t)((int)rintf(v) + 128) & 0xFFu) << (8 * b);
        }
        qwp[u] = pk;
    }
}

// ---------------- Kernel B: quantize + pack x into padded byte buffer ----------------
// Thread: 4 consecutive px of one row. float4 loads (coalesced 512 B runs/row),
// uint4 writes to padded interior.
__global__ __launch_bounds__(256) void quant_pack_x(const float4* __restrict__ x4,
                                                    uint4* __restrict__ qxp4) {
    int t = blockIdx.x * blockDim.x + threadIdx.x;   // 65536 threads
    int n = t >> 12;
    int rem = t & 4095;
    int h = rem >> 5;
    int wg = rem & 31;                               // group of 4 px
    uint32_t pk[4][8];
    #pragma unroll
    for (int pix = 0; pix < 4; ++pix)
        #pragma unroll
        for (int cg = 0; cg < 8; ++cg) pk[pix][cg] = 0u;
    #pragma unroll
    for (int c = 0; c < 32; ++c) {
        float4 v = x4[((size_t)(n * 32 + c) * 128 + h) * 32 + wg];
        int cg = c >> 2, sh = (c & 3) << 3;
        pk[0][cg] |= qbyte(v.x) << sh;
        pk[1][cg] |= qbyte(v.y) << sh;
        pk[2][cg] |= qbyte(v.z) << sh;
        pk[3][cg] |= qbyte(v.w) << sh;
    }
    size_t base = ((size_t)n * PIMG + (h + 1) * PROW + (wg * 4 + 1)) * 2;  // uint4 units
    #pragma unroll
    for (int pix = 0; pix < 4; ++pix) {
        qxp4[base + pix * 2 + 0] = make_uint4(pk[pix][0], pk[pix][1], pk[pix][2], pk[pix][3]);
        qxp4[base + pix * 2 + 1] = make_uint4(pk[pix][4], pk[pix][5], pk[pix][6], pk[pix][7]);
    }
}

// ---------------- Kernel C: barrier-free SAD conv ----------------
// 1024 blocks x 512 thr: tile 32x8, 1 px/thread x 2 filter-halves. NO LDS, NO
// __syncthreads: per kh, 6 transient global_load_dwordx4 from the L2-resident
// padded byte buffer (96 B span covers kw 0..2), counted-vmcnt pipelined by the
// compiler; weights via block-uniform s_load (independent lgkm counter).
// unroll 1 on kh keeps the window transient (18-load hoist = AGPR demotion, R8/R9).
__global__ __launch_bounds__(512, 8) void adder_conv(const uint32_t* __restrict__ qxp,
                                                     const uint32_t* __restrict__ qwp,
                                                     float* __restrict__ out) {
    int tid = threadIdx.x;
    // XCD-contiguous remap: XCD k owns 128 consecutive tiles (2 images).
    int b = ((blockIdx.x & 7) << 7) + (blockIdx.x >> 3);
    int n = b >> 6;
    int rem = b & 63;
    int h0 = (rem >> 2) * 8, w0 = (rem & 3) * 32;

    int fh = __builtin_amdgcn_readfirstlane(tid >> 8);  // filter half (wave-uniform)
    int px = tid & 255;
    int r = px >> 5;          // row in tile 0..7
    int c = px & 31;          // col in tile
    int gh = h0 + r, gw = w0 + c;

    // padded-coord (gh, gw) == image-coord (gh-1, gw-1): top-left tap of the 3x3
    const char* bbase = (const char*)qxp + ((size_t)n * PIMG + gh * PROW + gw) * 32;

    uint32_t acc[16];
    #pragma unroll
    for (int f = 0; f < 16; ++f) acc[f] = 0u;

    #pragma unroll 1
    for (int kh = 0; kh < 3; ++kh) {
        const uint4* rp = (const uint4*)(bbase + kh * (PROW * 32));
        uint4 p00 = rp[0], p01 = rp[1];   // kw=0
        uint4 p10 = rp[2], p11 = rp[3];   // kw=1
        uint4 p20 = rp[4], p21 = rp[5];   // kw=2
        #pragma unroll
        for (int kw = 0; kw < 3; ++kw) {
            uint4 x0 = (kw == 0) ? p00 : (kw == 1) ? p10 : p20;
            uint4 x1 = (kw == 0) ? p01 : (kw == 1) ? p11 : p21;
            const uint32_t* wt = qwp + ((kh * 3 + kw) * 32 + fh * 16) * 8;
            #pragma unroll
            for (int f = 0; f < 16; ++f) {
                const uint4* wp = (const uint4*)(wt + f * 8);
                uint4 wv0 = wp[0], wv1 = wp[1];
                uint32_t a = acc[f];
                a = sadu8(x0.x, wv0.x, a);
                a = sadu8(x0.y, wv0.y, a);
                a = sadu8(x0.z, wv0.z, a);
                a = sadu8(x0.w, wv0.w, a);
                a = sadu8(x1.x, wv1.x, a);
                a = sadu8(x1.y, wv1.y, a);
                a = sadu8(x1.z, wv1.z, a);
                a = sadu8(x1.w, wv1.w, a);
                acc[f] = a;
            }
        }
    }

    size_t obase = (((size_t)n * 32 + fh * 16) * 128 + gh) * 128 + gw;
    #pragma unroll
    for (int f = 0; f < 16; ++f) {
        out[obase + (size_t)f * 16384] = -(float)acc[f] * INPUT_SCALE;
    }
}

extern "C" void kernel_launch(void* const* d_in, const int* in_sizes, int n_in,
                              void* d_out, int out_size, void* d_ws, size_t ws_size,
                              hipStream_t stream) {
    const float* x = (const float*)d_in[0];       // (16,32,128,128)
    const float* w = (const float*)d_in[1];       // (32,32,3,3)
    float* out = (float*)d_out;                   // (16,32,128,128)

    uint32_t* qwp = (uint32_t*)d_ws;                          // 9216 B
    uint32_t* qxp = (uint32_t*)((char*)d_ws + 16384);         // 16*16900*32 B = 8.65 MB

    quant_weight_border<<<10, 1024, 0, stream>>>(w, qwp, qxp);
    quant_pack_x<<<256, 256, 0, stream>>>((const float4*)x, (uint4*)qxp);
    adder_conv<<<1024, 512, 0, stream>>>(qxp, qwp, out);
}